// Round 1
// baseline (323.097 us; speedup 1.0000x reference)
//
#include <hip/hip_runtime.h>

#define E  1024
#define H  64
#define BB 8
#define TT 2048

// ---------------- Projection: q,k,v = x @ W{q,k,v} ----------------
// C[16384x64]x3 = x[16384x1024] @ W[1024x64]
// 256 blocks x 512 threads; 64-row tile; K-chunk 64.
__global__ __launch_bounds__(512)
void proj_kernel(const float* __restrict__ x,
                 const float* __restrict__ Wq,
                 const float* __restrict__ Wk,
                 const float* __restrict__ Wv,
                 float* __restrict__ q,
                 float* __restrict__ k,
                 float* __restrict__ v)
{
    __shared__ float xs[64][64];        // 16 KB
    __shared__ float ws[3][64][64];     // 48 KB
    const int t  = threadIdx.x;
    const int c  = t & 63;              // output column (lane)
    const int rg = t >> 6;              // wave id 0..7 -> row group of 8
    const long row0 = (long)blockIdx.x * 64;
    const float* W[3] = {Wq, Wk, Wv};

    float acc0[8] = {}, acc1[8] = {}, acc2[8] = {};

    for (int k0 = 0; k0 < E; k0 += 64) {
        __syncthreads();   // protect LDS from previous iteration's readers
        // stage x tile: 4096 floats = 1024 float4, 2 per thread (coalesced)
        #pragma unroll
        for (int i = 0; i < 2; ++i) {
            int idx = t + i * 512;
            int r = idx >> 4, c4 = (idx & 15) << 2;
            *(float4*)&xs[r][c4] =
                *(const float4*)&x[(row0 + r) * E + k0 + c4];
        }
        // stage W tiles: each 64x64 tile is a contiguous 4096-float block
        #pragma unroll
        for (int w = 0; w < 3; ++w) {
            #pragma unroll
            for (int i = 0; i < 2; ++i) {
                int idx = t + i * 512;
                *(float4*)&ws[w][0][idx << 2] =
                    *(const float4*)&W[w][(long)k0 * H + (idx << 2)];
            }
        }
        __syncthreads();
        #pragma unroll 8
        for (int kk = 0; kk < 64; ++kk) {
            float w0 = ws[0][kk][c];   // lanes consecutive -> conflict-free
            float w1 = ws[1][kk][c];
            float w2 = ws[2][kk][c];
            #pragma unroll
            for (int i = 0; i < 8; ++i) {
                float xv = xs[rg * 8 + i][kk];   // wave-uniform -> broadcast
                acc0[i] = fmaf(xv, w0, acc0[i]);
                acc1[i] = fmaf(xv, w1, acc1[i]);
                acc2[i] = fmaf(xv, w2, acc2[i]);
            }
        }
    }
    const float qscale = 0.125f;   // 1/sqrt(H)
    #pragma unroll
    for (int i = 0; i < 8; ++i) {
        long off = (row0 + rg * 8 + i) * H + c;
        q[off] = acc0[i] * qscale;
        k[off] = acc1[i];
        v[off] = acc2[i];
    }
}

// ---------------- Flash attention (fp32, causal) ----------------
// grid (32, 8): block handles subtile pair (j, 63-j), 32 q-rows each,
// so every block visits exactly 33 key tiles (load-balanced).
__global__ __launch_bounds__(512)
void attn_kernel(const float* __restrict__ q,
                 const float* __restrict__ k,
                 const float* __restrict__ v,
                 float* __restrict__ out)
{
    __shared__ float qs[32][65];
    __shared__ float ks[64][65];
    __shared__ float vs[64][65];
    __shared__ float ss[32][65];
    __shared__ float ms[32], ls[32], fs[32];

    const int t    = threadIdx.x;
    const int b    = blockIdx.y;
    const int lane = t & 63;
    const int rg   = t >> 6;          // 0..7

    for (int pass = 0; pass < 2; ++pass) {
        const int st = (pass == 0) ? (int)blockIdx.x : 63 - (int)blockIdx.x;
        const int q0 = st * 32;

        // load q subtile: 2048 floats = 512 float4, 1 per thread
        {
            int r = t >> 4, c4 = (t & 15) << 2;
            *(float4*)&qs[r][c4] =
                *(const float4*)&q[((long)b * TT + q0 + r) * H + c4];
        }
        if (t < 32) { ms[t] = -1e30f; ls[t] = 0.f; }
        float o[4] = {0.f, 0.f, 0.f, 0.f};

        const int nkt = ((q0 + 31) >> 6) + 1;
        for (int kt = 0; kt < nkt; ++kt) {
            const int k0 = kt << 6;
            __syncthreads();   // prev PV / q-load / init visible
            #pragma unroll
            for (int i = 0; i < 2; ++i) {
                int idx = t + i * 512;
                int s = idx >> 4, c4 = (idx & 15) << 2;
                long g = ((long)b * TT + k0 + s) * H + c4;
                *(float4*)&ks[s][c4] = *(const float4*)&k[g];
                *(float4*)&vs[s][c4] = *(const float4*)&v[g];
            }
            __syncthreads();
            // ---- scores: thread computes 2x2 block of S ----
            {
                const int r0 = (t >> 5) * 2;   // 0..30
                const int c0 = (t & 31) * 2;   // 0..62
                float s00 = 0, s01 = 0, s10 = 0, s11 = 0;
                #pragma unroll 16
                for (int e = 0; e < H; ++e) {
                    float qa = qs[r0][e],   qb = qs[r0 + 1][e];
                    float ka = ks[c0][e],   kb = ks[c0 + 1][e];
                    s00 = fmaf(qa, ka, s00); s01 = fmaf(qa, kb, s01);
                    s10 = fmaf(qb, ka, s10); s11 = fmaf(qb, kb, s11);
                }
                const int qi = q0 + r0, ki = k0 + c0;
                ss[r0][c0]         = (ki     <= qi    ) ? s00 : -1e30f;
                ss[r0][c0 + 1]     = (ki + 1 <= qi    ) ? s01 : -1e30f;
                ss[r0 + 1][c0]     = (ki     <= qi + 1) ? s10 : -1e30f;
                ss[r0 + 1][c0 + 1] = (ki + 1 <= qi + 1) ? s11 : -1e30f;
            }
            __syncthreads();
            // ---- online softmax stats: 16 lanes per row ----
            {
                const int row  = t >> 4;     // 0..31
                const int part = t & 15;
                float p0 = ss[row][part * 4],     p1 = ss[row][part * 4 + 1];
                float p2 = ss[row][part * 4 + 2], p3 = ss[row][part * 4 + 3];
                float mx = fmaxf(fmaxf(p0, p1), fmaxf(p2, p3));
                #pragma unroll
                for (int d = 1; d < 16; d <<= 1)
                    mx = fmaxf(mx, __shfl_xor(mx, d, 64));
                const float mold = ms[row];
                const float mnew = fmaxf(mold, mx);
                p0 = __expf(p0 - mnew); p1 = __expf(p1 - mnew);
                p2 = __expf(p2 - mnew); p3 = __expf(p3 - mnew);
                ss[row][part * 4]     = p0; ss[row][part * 4 + 1] = p1;
                ss[row][part * 4 + 2] = p2; ss[row][part * 4 + 3] = p3;
                float sm = p0 + p1 + p2 + p3;
                #pragma unroll
                for (int d = 1; d < 16; d <<= 1)
                    sm += __shfl_xor(sm, d, 64);
                if (part == 0) {
                    float f = __expf(mold - mnew);
                    ms[row] = mnew;
                    ls[row] = ls[row] * f + sm;
                    fs[row] = f;
                }
            }
            __syncthreads();
            // ---- PV: thread owns col `lane`, rows rg*4..rg*4+3 ----
            {
                const int r0 = rg * 4;
                o[0] *= fs[r0];     o[1] *= fs[r0 + 1];
                o[2] *= fs[r0 + 2]; o[3] *= fs[r0 + 3];
                #pragma unroll 8
                for (int s = 0; s < 64; ++s) {
                    float vv = vs[s][lane];
                    o[0] = fmaf(ss[r0][s],     vv, o[0]);
                    o[1] = fmaf(ss[r0 + 1][s], vv, o[1]);
                    o[2] = fmaf(ss[r0 + 2][s], vv, o[2]);
                    o[3] = fmaf(ss[r0 + 3][s], vv, o[3]);
                }
            }
        }
        __syncthreads();   // ls final, PV done
        {
            const int r0 = rg * 4;
            #pragma unroll
            for (int ii = 0; ii < 4; ++ii) {
                float inv = 1.0f / ls[r0 + ii];
                out[((long)b * TT + q0 + r0 + ii) * H + lane] = o[ii] * inv;
            }
        }
        __syncthreads();   // out-write read ls; next pass re-inits ls/qs
    }
}

extern "C" void kernel_launch(void* const* d_in, const int* in_sizes, int n_in,
                              void* d_out, int out_size, void* d_ws, size_t ws_size,
                              hipStream_t stream)
{
    const float* x  = (const float*)d_in[0];
    const float* Wq = (const float*)d_in[1];
    const float* Wk = (const float*)d_in[2];
    const float* Wv = (const float*)d_in[3];
    float* out = (float*)d_out;

    const size_t n = (size_t)BB * TT * H;   // 1,048,576 per tensor
    float* q = (float*)d_ws;
    float* k = q + n;
    float* v = k + n;

    proj_kernel<<<dim3(BB * TT / 64), 512, 0, stream>>>(x, Wq, Wk, Wv, q, k, v);
    attn_kernel<<<dim3(32, BB), 512, 0, stream>>>(q, k, v, out);
}

// Round 2
// 191.952 us; speedup vs baseline: 1.6832x; 1.6832x over previous
//
#include <hip/hip_runtime.h>

#define E  1024
#define H  64
#define BB 8
#define TT 2048
#define QBLK 32
#define KVB 128

typedef __attribute__((ext_vector_type(8))) short bf16x8;
typedef __attribute__((ext_vector_type(4))) float f32x4;
typedef __attribute__((ext_vector_type(8))) short short8;
typedef __attribute__((ext_vector_type(4))) short short4v;

__device__ __forceinline__ short f2bf(float f) {
    union { float f; unsigned u; } v; v.f = f;
    unsigned r = v.u + 0x7FFFu + ((v.u >> 16) & 1u);   // RNE
    return (short)(r >> 16);
}

// ---------------- Projection: q,k,v = x @ W{q,k,v} (fp32 compute, bf16 out) ---
__global__ __launch_bounds__(512)
void proj_kernel(const float* __restrict__ x,
                 const float* __restrict__ Wq,
                 const float* __restrict__ Wk,
                 const float* __restrict__ Wv,
                 short* __restrict__ q,
                 short* __restrict__ k,
                 short* __restrict__ v)
{
    __shared__ float xs[64][64];
    __shared__ float ws[3][64][64];
    const int t  = threadIdx.x;
    const int c  = t & 63;
    const int rg = t >> 6;
    const long row0 = (long)blockIdx.x * 64;
    const float* W[3] = {Wq, Wk, Wv};

    float acc0[8] = {}, acc1[8] = {}, acc2[8] = {};

    for (int k0 = 0; k0 < E; k0 += 64) {
        __syncthreads();
        #pragma unroll
        for (int i = 0; i < 2; ++i) {
            int idx = t + i * 512;
            int r = idx >> 4, c4 = (idx & 15) << 2;
            *(float4*)&xs[r][c4] =
                *(const float4*)&x[(row0 + r) * E + k0 + c4];
        }
        #pragma unroll
        for (int w = 0; w < 3; ++w) {
            #pragma unroll
            for (int i = 0; i < 2; ++i) {
                int idx = t + i * 512;
                *(float4*)&ws[w][0][idx << 2] =
                    *(const float4*)&W[w][(long)k0 * H + (idx << 2)];
            }
        }
        __syncthreads();
        #pragma unroll 8
        for (int kk = 0; kk < 64; ++kk) {
            float w0 = ws[0][kk][c];
            float w1 = ws[1][kk][c];
            float w2 = ws[2][kk][c];
            #pragma unroll
            for (int i = 0; i < 8; ++i) {
                float xv = xs[rg * 8 + i][kk];
                acc0[i] = fmaf(xv, w0, acc0[i]);
                acc1[i] = fmaf(xv, w1, acc1[i]);
                acc2[i] = fmaf(xv, w2, acc2[i]);
            }
        }
    }
    const float qscale = 0.125f;   // 1/sqrt(H), folded into q
    #pragma unroll
    for (int i = 0; i < 8; ++i) {
        long off = (row0 + rg * 8 + i) * H + c;
        q[off] = f2bf(acc0[i] * qscale);
        k[off] = f2bf(acc1[i]);
        v[off] = f2bf(acc2[i]);
    }
}

// ---------------- MFMA flash attention (bf16, causal) ----------------
// 4 waves: (wr 0..1) q-row-groups x (wc 0..1) kv-halves. QBLK=32, KVB=128.
__global__ __launch_bounds__(256)
void attn_mfma(const short* __restrict__ qg,
               const short* __restrict__ kg,
               const short* __restrict__ vg,
               float* __restrict__ out)
{
    __shared__ short Ks[KVB * 64];      // [kv][e]  swizzled elem^=((kv&7)<<3)
    __shared__ short Vt[64 * KVB];      // [h][kv]  swizzled elem^=((h&7)<<3)
    __shared__ short Ps[4][16 * 64];    // per-wave P[ql][kv], swizzled
    __shared__ float ms_[2][32], ls_[2][32];
    __shared__ float Op[32][65];

    const int t   = threadIdx.x;
    const int L   = t & 63;
    const int wid = t >> 6;
    const int wr  = wid >> 1, wc = wid & 1;
    const int b   = blockIdx.y;
    const int st  = 63 - (int)blockIdx.x;   // descending work order (LPT)
    const int q0  = st * QBLK;
    const int l15 = L & 15, g = L >> 4;

    // Q fragments hoisted to registers (A-layout: row=l15, k=g*8+j)
    bf16x8 qf[2];
    {
        const int qrow = q0 + wr * 16 + l15;
        const short* qp = qg + ((long)b * TT + qrow) * 64 + g * 8;
        qf[0] = *(const bf16x8*)(qp);
        qf[1] = *(const bf16x8*)(qp + 32);
    }

    const f32x4 zero4 = {0.f, 0.f, 0.f, 0.f};
    f32x4 o[4] = {zero4, zero4, zero4, zero4};
    float mrun[4], lrun[4];
    #pragma unroll
    for (int r = 0; r < 4; ++r) { mrun[r] = -1e30f; lrun[r] = 0.f; }

    const int nkt = (q0 + QBLK - 1) / KVB + 1;
    for (int kt = 0; kt < nkt; ++kt) {
        const int k0 = kt * KVB;

        // ---- stage K tile [128][64] bf16, swizzled ----
        {
            const int chunk = t & 7, kvb = t >> 3;   // kvb 0..31
            #pragma unroll
            for (int i = 0; i < 4; ++i) {
                int kvr = kvb + i * 32;
                short8 val = *(const short8*)&kg[((long)b * TT + k0 + kvr) * 64 + chunk * 8];
                int el = (kvr * 64 + chunk * 8) ^ ((kvr & 7) << 3);
                *(short8*)&Ks[el] = val;
            }
        }
        // ---- stage V transposed [64][128] bf16, swizzled ----
        {
            const int hb = (t & 15) * 4, kvp = (t >> 4) * 2;
            #pragma unroll
            for (int i = 0; i < 4; ++i) {
                int kv0 = kvp + i * 32;
                short4v a0 = *(const short4v*)&vg[((long)b * TT + k0 + kv0) * 64 + hb];
                short4v a1 = *(const short4v*)&vg[((long)b * TT + k0 + kv0 + 1) * 64 + hb];
                #pragma unroll
                for (int j = 0; j < 4; ++j) {
                    int h = hb + j;
                    int el = (h * KVB + kv0) ^ ((h & 7) << 3);
                    unsigned pk = (unsigned)(unsigned short)a0[j] |
                                  ((unsigned)(unsigned short)a1[j] << 16);
                    *(unsigned*)&Vt[el] = pk;
                }
            }
        }
        __syncthreads();   // B: staging visible

        const bool active = (k0 + wc * 64) <= (q0 + QBLK - 1);
        f32x4 s[4];
        float mloc[4];
        if (active) {
            #pragma unroll
            for (int c = 0; c < 4; ++c) s[c] = zero4;
            #pragma unroll
            for (int c = 0; c < 4; ++c) {
                const int kvl = wc * 64 + c * 16 + l15;
                #pragma unroll
                for (int kc = 0; kc < 2; ++kc) {
                    int el = (kvl * 64 + kc * 32 + g * 8) ^ ((kvl & 7) << 3);
                    bf16x8 kf = *(const bf16x8*)&Ks[el];
                    s[c] = __builtin_amdgcn_mfma_f32_16x16x32_bf16(qf[kc], kf, s[c], 0, 0, 0);
                }
            }
            if (k0 + KVB > q0) {   // tile overlaps diagonal -> mask
                #pragma unroll
                for (int c = 0; c < 4; ++c) {
                    const int kvg = k0 + wc * 64 + c * 16 + l15;
                    #pragma unroll
                    for (int r = 0; r < 4; ++r) {
                        const int qgr = q0 + wr * 16 + g * 4 + r;
                        if (kvg > qgr) s[c][r] = -1e30f;
                    }
                }
            }
            #pragma unroll
            for (int r = 0; r < 4; ++r) {
                float m = fmaxf(fmaxf(s[0][r], s[1][r]), fmaxf(s[2][r], s[3][r]));
                m = fmaxf(m, __shfl_xor(m, 1));
                m = fmaxf(m, __shfl_xor(m, 2));
                m = fmaxf(m, __shfl_xor(m, 4));
                m = fmaxf(m, __shfl_xor(m, 8));
                mloc[r] = m;
            }
        } else {
            #pragma unroll
            for (int r = 0; r < 4; ++r) mloc[r] = -1e30f;
        }
        if (l15 == 0) {
            #pragma unroll
            for (int r = 0; r < 4; ++r) ms_[wc][wr * 16 + g * 4 + r] = mloc[r];
        }
        __syncthreads();   // C: m stats visible

        float alpha[4];
        #pragma unroll
        for (int r = 0; r < 4; ++r) {
            const int row = wr * 16 + g * 4 + r;
            float mnew = fmaxf(mrun[r], fmaxf(ms_[0][row], ms_[1][row]));
            alpha[r] = __expf(mrun[r] - mnew);
            mrun[r] = mnew;
            #pragma unroll
            for (int nf = 0; nf < 4; ++nf) o[nf][r] *= alpha[r];
        }

        if (active) {
            float lsum[4] = {0.f, 0.f, 0.f, 0.f};
            #pragma unroll
            for (int c = 0; c < 4; ++c)
                #pragma unroll
                for (int r = 0; r < 4; ++r) {
                    float p = __expf(s[c][r] - mrun[r]);
                    s[c][r] = p;
                    lsum[r] += p;
                }
            #pragma unroll
            for (int r = 0; r < 4; ++r) {
                lsum[r] += __shfl_xor(lsum[r], 1);
                lsum[r] += __shfl_xor(lsum[r], 2);
                lsum[r] += __shfl_xor(lsum[r], 4);
                lsum[r] += __shfl_xor(lsum[r], 8);
            }
            if (l15 == 0) {
                #pragma unroll
                for (int r = 0; r < 4; ++r) ls_[wc][wr * 16 + g * 4 + r] = lsum[r];
            }
            // write P (bf16) to wave-local LDS (DS ops in-order per wave)
            #pragma unroll
            for (int c = 0; c < 4; ++c)
                #pragma unroll
                for (int r = 0; r < 4; ++r) {
                    const int ql = g * 4 + r, kvl = c * 16 + l15;
                    const int el = (ql * 64 + kvl) ^ ((ql & 7) << 3);
                    Ps[wid][el] = f2bf(s[c][r]);
                }
            // PV MFMAs accumulate into o
            #pragma unroll
            for (int kc = 0; kc < 2; ++kc) {
                const int pe = (l15 * 64 + kc * 32 + g * 8) ^ ((l15 & 7) << 3);
                bf16x8 pa = *(const bf16x8*)&Ps[wid][pe];
                #pragma unroll
                for (int nf = 0; nf < 4; ++nf) {
                    const int h = nf * 16 + l15;
                    const int ve = (h * KVB + wc * 64 + kc * 32 + g * 8) ^ ((h & 7) << 3);
                    bf16x8 vb = *(const bf16x8*)&Vt[ve];
                    o[nf] = __builtin_amdgcn_mfma_f32_16x16x32_bf16(pa, vb, o[nf], 0, 0, 0);
                }
            }
        } else {
            if (l15 == 0) {
                #pragma unroll
                for (int r = 0; r < 4; ++r) ls_[wc][wr * 16 + g * 4 + r] = 0.f;
            }
        }
        __syncthreads();   // D: l stats visible; PV reads done -> restage safe

        #pragma unroll
        for (int r = 0; r < 4; ++r) {
            const int row = wr * 16 + g * 4 + r;
            lrun[r] = lrun[r] * alpha[r] + ls_[0][row] + ls_[1][row];
        }
    }

    // ---- cross-wc O reduction + store ----
    if (wc == 0) {
        #pragma unroll
        for (int nf = 0; nf < 4; ++nf)
            #pragma unroll
            for (int r = 0; r < 4; ++r)
                Op[wr * 16 + g * 4 + r][nf * 16 + l15] = o[nf][r];
    }
    __syncthreads();
    if (wc == 1) {
        #pragma unroll
        for (int r = 0; r < 4; ++r) {
            const int row = wr * 16 + g * 4 + r;
            const float inv = 1.0f / lrun[r];
            #pragma unroll
            for (int nf = 0; nf < 4; ++nf) {
                const int h = nf * 16 + l15;
                out[((long)b * TT + q0 + row) * 64 + h] = (o[nf][r] + Op[row][h]) * inv;
            }
        }
    }
}

extern "C" void kernel_launch(void* const* d_in, const int* in_sizes, int n_in,
                              void* d_out, int out_size, void* d_ws, size_t ws_size,
                              hipStream_t stream)
{
    const float* x  = (const float*)d_in[0];
    const float* Wq = (const float*)d_in[1];
    const float* Wk = (const float*)d_in[2];
    const float* Wv = (const float*)d_in[3];
    float* out = (float*)d_out;

    const size_t n = (size_t)BB * TT * H;   // 1,048,576 per tensor
    short* q = (short*)d_ws;
    short* k = q + n;
    short* v = k + n;

    proj_kernel<<<dim3(BB * TT / 64), 512, 0, stream>>>(x, Wq, Wk, Wv, q, k, v);
    attn_mfma<<<dim3(64, BB), 256, 0, stream>>>(q, k, v, out);
}

// Round 3
// 104.722 us; speedup vs baseline: 3.0853x; 1.8330x over previous
//
#include <hip/hip_runtime.h>

#define E  1024
#define H  64
#define BB 8
#define TT 2048
#define QBLK 32
#define KVB 128

typedef __attribute__((ext_vector_type(8))) short bf16x8;
typedef __attribute__((ext_vector_type(4))) float f32x4;
typedef __attribute__((ext_vector_type(8))) short short8;
typedef __attribute__((ext_vector_type(4))) short short4v;

__device__ __forceinline__ short f2bf(float f) {
    union { float f; unsigned u; } v; v.f = f;
    unsigned r = v.u + 0x7FFFu + ((v.u >> 16) & 1u);   // RNE
    return (short)(r >> 16);
}

// ---- pack W into B-fragment layout for mfma_f32_16x16x32_bf16 ----
// Wb[((K*12 + f)*64 + l)*8 + j] = bf16( W[f>>2][(K*32 + (l>>4)*8 + j)*64 + (f&3)*16 + (l&15)] )
__global__ __launch_bounds__(256)
void pack_w(const float* __restrict__ Wq, const float* __restrict__ Wk,
            const float* __restrict__ Wv, short* __restrict__ Wb)
{
    const int t  = blockIdx.x * 256 + threadIdx.x;   // 24576 total
    const int l  = t & 63;
    const int f  = (t >> 6) % 12;
    const int kc = t / 768;                          // kchunk 0..31
    const float* W = (f < 4) ? Wq : ((f < 8) ? Wk : Wv);
    const int e0 = kc * 32 + ((l >> 4) << 3);
    const int n  = ((f & 3) << 4) + (l & 15);
    short8 o;
    #pragma unroll
    for (int j = 0; j < 8; ++j) o[j] = f2bf(W[(e0 + j) * 64 + n]);
    *(short8*)&Wb[(size_t)t * 8] = o;
}

// ---- split-K MFMA projection ----
// grid 512 x 256 thr. wave (wm, kh): rows blk*32+wm*16..+16, kchunks kh*16..+16,
// all 192 output cols (12 fragments). No LDS / no barriers in main loop.
__global__ __launch_bounds__(256)
void proj_mfma(const float* __restrict__ x, const short* __restrict__ Wb,
               short* __restrict__ q, short* __restrict__ k, short* __restrict__ v)
{
    __shared__ float part[2][12][64][4];   // 24 KB: kh=1 partials
    const int t   = threadIdx.x;
    const int l   = t & 63;
    const int wid = t >> 6;
    const int wm  = wid & 1, kh = wid >> 1;
    const long row0 = (long)blockIdx.x * 32 + wm * 16;
    const int l15 = l & 15, g = l >> 4;

    f32x4 acc[12];
    #pragma unroll
    for (int f = 0; f < 12; ++f) acc[f] = (f32x4){0.f, 0.f, 0.f, 0.f};

    const float* xp = x + (row0 + l15) * E + kh * 512 + g * 8;
    const short* wp = Wb + (size_t)(kh * 16) * 12 * 512 + (size_t)l * 8;

    for (int kc = 0; kc < 16; ++kc) {
        float4 a0 = *(const float4*)(xp);
        float4 a1 = *(const float4*)(xp + 4);
        xp += 32;
        bf16x8 af;
        af[0] = f2bf(a0.x); af[1] = f2bf(a0.y); af[2] = f2bf(a0.z); af[3] = f2bf(a0.w);
        af[4] = f2bf(a1.x); af[5] = f2bf(a1.y); af[6] = f2bf(a1.z); af[7] = f2bf(a1.w);
        #pragma unroll
        for (int f = 0; f < 12; ++f) {
            bf16x8 bf = *(const bf16x8*)(wp + (size_t)f * 512);
            acc[f] = __builtin_amdgcn_mfma_f32_16x16x32_bf16(af, bf, acc[f], 0, 0, 0);
        }
        wp += 12 * 512;
    }

    if (kh == 1) {
        #pragma unroll
        for (int f = 0; f < 12; ++f)
            *(f32x4*)&part[wm][f][l][0] = acc[f];
    }
    __syncthreads();
    if (kh == 0) {
        #pragma unroll
        for (int f = 0; f < 12; ++f)
            acc[f] += *(const f32x4*)&part[wm][f][l][0];
        #pragma unroll
        for (int f = 0; f < 12; ++f) {
            const int m = f >> 2;
            const int h = ((f & 3) << 4) + l15;
            short* base = (m == 0) ? q : (m == 1 ? k : v);
            const float sc = (m == 0) ? 0.125f : 1.0f;   // fold 1/sqrt(H) into q
            #pragma unroll
            for (int r = 0; r < 4; ++r) {
                const long row = row0 + g * 4 + r;
                base[row * 64 + h] = f2bf(acc[f][r] * sc);
            }
        }
    }
}

// ---------------- MFMA flash attention (bf16, causal) ----------------
// 4 waves: (wr 0..1) q-row-groups x (wc 0..1) kv-halves. QBLK=32, KVB=128.
__global__ __launch_bounds__(256)
void attn_mfma(const short* __restrict__ qg,
               const short* __restrict__ kg,
               const short* __restrict__ vg,
               float* __restrict__ out)
{
    __shared__ short Ks[KVB * 64];      // [kv][e]  swizzled elem^=((kv&7)<<3)
    __shared__ short Vt[64 * KVB];      // [h][kv]  swizzled elem^=((h&7)<<3)
    __shared__ short Ps[4][16 * 64];    // per-wave P[ql][kv], swizzled
    __shared__ float ms_[2][32], ls_[2][32];
    __shared__ float Op[32][65];

    const int t   = threadIdx.x;
    const int L   = t & 63;
    const int wid = t >> 6;
    const int wr  = wid >> 1, wc = wid & 1;
    const int b   = blockIdx.y;
    const int st  = 63 - (int)blockIdx.x;   // descending work order (LPT)
    const int q0  = st * QBLK;
    const int l15 = L & 15, g = L >> 4;

    bf16x8 qf[2];
    {
        const int qrow = q0 + wr * 16 + l15;
        const short* qp = qg + ((long)b * TT + qrow) * 64 + g * 8;
        qf[0] = *(const bf16x8*)(qp);
        qf[1] = *(const bf16x8*)(qp + 32);
    }

    const f32x4 zero4 = {0.f, 0.f, 0.f, 0.f};
    f32x4 o[4] = {zero4, zero4, zero4, zero4};
    float mrun[4], lrun[4];
    #pragma unroll
    for (int r = 0; r < 4; ++r) { mrun[r] = -1e30f; lrun[r] = 0.f; }

    const int nkt = (q0 + QBLK - 1) / KVB + 1;
    for (int kt = 0; kt < nkt; ++kt) {
        const int k0 = kt * KVB;

        {
            const int chunk = t & 7, kvb = t >> 3;
            #pragma unroll
            for (int i = 0; i < 4; ++i) {
                int kvr = kvb + i * 32;
                short8 val = *(const short8*)&kg[((long)b * TT + k0 + kvr) * 64 + chunk * 8];
                int el = (kvr * 64 + chunk * 8) ^ ((kvr & 7) << 3);
                *(short8*)&Ks[el] = val;
            }
        }
        {
            const int hb = (t & 15) * 4, kvp = (t >> 4) * 2;
            #pragma unroll
            for (int i = 0; i < 4; ++i) {
                int kv0 = kvp + i * 32;
                short4v a0 = *(const short4v*)&vg[((long)b * TT + k0 + kv0) * 64 + hb];
                short4v a1 = *(const short4v*)&vg[((long)b * TT + k0 + kv0 + 1) * 64 + hb];
                #pragma unroll
                for (int j = 0; j < 4; ++j) {
                    int h = hb + j;
                    int el = (h * KVB + kv0) ^ ((h & 7) << 3);
                    unsigned pk = (unsigned)(unsigned short)a0[j] |
                                  ((unsigned)(unsigned short)a1[j] << 16);
                    *(unsigned*)&Vt[el] = pk;
                }
            }
        }
        __syncthreads();

        const bool active = (k0 + wc * 64) <= (q0 + QBLK - 1);
        f32x4 s[4];
        float mloc[4];
        if (active) {
            #pragma unroll
            for (int c = 0; c < 4; ++c) s[c] = zero4;
            #pragma unroll
            for (int c = 0; c < 4; ++c) {
                const int kvl = wc * 64 + c * 16 + l15;
                #pragma unroll
                for (int kc = 0; kc < 2; ++kc) {
                    int el = (kvl * 64 + kc * 32 + g * 8) ^ ((kvl & 7) << 3);
                    bf16x8 kf = *(const bf16x8*)&Ks[el];
                    s[c] = __builtin_amdgcn_mfma_f32_16x16x32_bf16(qf[kc], kf, s[c], 0, 0, 0);
                }
            }
            if (k0 + KVB > q0) {
                #pragma unroll
                for (int c = 0; c < 4; ++c) {
                    const int kvg = k0 + wc * 64 + c * 16 + l15;
                    #pragma unroll
                    for (int r = 0; r < 4; ++r) {
                        const int qgr = q0 + wr * 16 + g * 4 + r;
                        if (kvg > qgr) s[c][r] = -1e30f;
                    }
                }
            }
            #pragma unroll
            for (int r = 0; r < 4; ++r) {
                float m = fmaxf(fmaxf(s[0][r], s[1][r]), fmaxf(s[2][r], s[3][r]));
                m = fmaxf(m, __shfl_xor(m, 1));
                m = fmaxf(m, __shfl_xor(m, 2));
                m = fmaxf(m, __shfl_xor(m, 4));
                m = fmaxf(m, __shfl_xor(m, 8));
                mloc[r] = m;
            }
        } else {
            #pragma unroll
            for (int r = 0; r < 4; ++r) mloc[r] = -1e30f;
        }
        if (l15 == 0) {
            #pragma unroll
            for (int r = 0; r < 4; ++r) ms_[wc][wr * 16 + g * 4 + r] = mloc[r];
        }
        __syncthreads();

        float alpha[4];
        #pragma unroll
        for (int r = 0; r < 4; ++r) {
            const int row = wr * 16 + g * 4 + r;
            float mnew = fmaxf(mrun[r], fmaxf(ms_[0][row], ms_[1][row]));
            alpha[r] = __expf(mrun[r] - mnew);
            mrun[r] = mnew;
            #pragma unroll
            for (int nf = 0; nf < 4; ++nf) o[nf][r] *= alpha[r];
        }

        if (active) {
            float lsum[4] = {0.f, 0.f, 0.f, 0.f};
            #pragma unroll
            for (int c = 0; c < 4; ++c)
                #pragma unroll
                for (int r = 0; r < 4; ++r) {
                    float p = __expf(s[c][r] - mrun[r]);
                    s[c][r] = p;
                    lsum[r] += p;
                }
            #pragma unroll
            for (int r = 0; r < 4; ++r) {
                lsum[r] += __shfl_xor(lsum[r], 1);
                lsum[r] += __shfl_xor(lsum[r], 2);
                lsum[r] += __shfl_xor(lsum[r], 4);
                lsum[r] += __shfl_xor(lsum[r], 8);
            }
            if (l15 == 0) {
                #pragma unroll
                for (int r = 0; r < 4; ++r) ls_[wc][wr * 16 + g * 4 + r] = lsum[r];
            }
            #pragma unroll
            for (int c = 0; c < 4; ++c)
                #pragma unroll
                for (int r = 0; r < 4; ++r) {
                    const int ql = g * 4 + r, kvl = c * 16 + l15;
                    const int el = (ql * 64 + kvl) ^ ((ql & 7) << 3);
                    Ps[wid][el] = f2bf(s[c][r]);
                }
            #pragma unroll
            for (int kc = 0; kc < 2; ++kc) {
                const int pe = (l15 * 64 + kc * 32 + g * 8) ^ ((l15 & 7) << 3);
                bf16x8 pa = *(const bf16x8*)&Ps[wid][pe];
                #pragma unroll
                for (int nf = 0; nf < 4; ++nf) {
                    const int h = nf * 16 + l15;
                    const int ve = (h * KVB + wc * 64 + kc * 32 + g * 8) ^ ((h & 7) << 3);
                    bf16x8 vb = *(const bf16x8*)&Vt[ve];
                    o[nf] = __builtin_amdgcn_mfma_f32_16x16x32_bf16(pa, vb, o[nf], 0, 0, 0);
                }
            }
        } else {
            if (l15 == 0) {
                #pragma unroll
                for (int r = 0; r < 4; ++r) ls_[wc][wr * 16 + g * 4 + r] = 0.f;
            }
        }
        __syncthreads();

        #pragma unroll
        for (int r = 0; r < 4; ++r) {
            const int row = wr * 16 + g * 4 + r;
            lrun[r] = lrun[r] * alpha[r] + ls_[0][row] + ls_[1][row];
        }
    }

    if (wc == 0) {
        #pragma unroll
        for (int nf = 0; nf < 4; ++nf)
            #pragma unroll
            for (int r = 0; r < 4; ++r)
                Op[wr * 16 + g * 4 + r][nf * 16 + l15] = o[nf][r];
    }
    __syncthreads();
    if (wc == 1) {
        #pragma unroll
        for (int r = 0; r < 4; ++r) {
            const int row = wr * 16 + g * 4 + r;
            const float inv = 1.0f / lrun[r];
            #pragma unroll
            for (int nf = 0; nf < 4; ++nf) {
                const int h = nf * 16 + l15;
                out[((long)b * TT + q0 + row) * 64 + h] = (o[nf][r] + Op[row][h]) * inv;
            }
        }
    }
}

extern "C" void kernel_launch(void* const* d_in, const int* in_sizes, int n_in,
                              void* d_out, int out_size, void* d_ws, size_t ws_size,
                              hipStream_t stream)
{
    const float* x  = (const float*)d_in[0];
    const float* Wq = (const float*)d_in[1];
    const float* Wk = (const float*)d_in[2];
    const float* Wv = (const float*)d_in[3];
    float* out = (float*)d_out;

    const size_t n = (size_t)BB * TT * H;   // 1,048,576 per tensor
    short* q  = (short*)d_ws;
    short* k  = q + n;
    short* v  = k + n;
    short* Wb = v + n;                      // 196,608 shorts

    pack_w   <<<dim3(96),        256, 0, stream>>>(Wq, Wk, Wv, Wb);
    proj_mfma<<<dim3(512),       256, 0, stream>>>(x, Wb, q, k, v);
    attn_mfma<<<dim3(64, BB),    256, 0, stream>>>(q, k, v, out);
}

// Round 4
// 88.450 us; speedup vs baseline: 3.6529x; 1.1840x over previous
//
#include <hip/hip_runtime.h>

#define E  1024
#define H  64
#define BB 8
#define TT 2048

typedef __attribute__((ext_vector_type(8))) short bf16x8;
typedef __attribute__((ext_vector_type(4))) float f32x4;
typedef __attribute__((ext_vector_type(8))) short short8;
typedef __attribute__((ext_vector_type(4))) short short4v;

__device__ __forceinline__ short f2bf(float f) {
    union { float f; unsigned u; } v; v.f = f;
    unsigned r = v.u + 0x7FFFu + ((v.u >> 16) & 1u);   // RNE
    return (short)(r >> 16);
}

// ---- pack W into B-fragment layout for mfma_f32_16x16x32_bf16 ----
__global__ __launch_bounds__(256)
void pack_w(const float* __restrict__ Wq, const float* __restrict__ Wk,
            const float* __restrict__ Wv, short* __restrict__ Wb)
{
    const int t  = blockIdx.x * 256 + threadIdx.x;   // 24576 total
    const int l  = t & 63;
    const int f  = (t >> 6) % 12;
    const int kc = t / 768;                          // kchunk 0..31
    const float* W = (f < 4) ? Wq : ((f < 8) ? Wk : Wv);
    const int e0 = kc * 32 + ((l >> 4) << 3);
    const int n  = ((f & 3) << 4) + (l & 15);
    short8 o;
    #pragma unroll
    for (int j = 0; j < 8; ++j) o[j] = f2bf(W[(e0 + j) * 64 + n]);
    *(short8*)&Wb[(size_t)t * 8] = o;
}

// ---- split-K MFMA projection; writes q,k row-major and V TRANSPOSED ----
__global__ __launch_bounds__(256)
void proj_mfma(const float* __restrict__ x, const short* __restrict__ Wb,
               short* __restrict__ q, short* __restrict__ k, short* __restrict__ vt)
{
    __shared__ float part[2][12][64][4];   // 24 KB: kh=1 partials
    const int t   = threadIdx.x;
    const int l   = t & 63;
    const int wid = t >> 6;
    const int wm  = wid & 1, kh = wid >> 1;
    const long row0 = (long)blockIdx.x * 32 + wm * 16;
    const int l15 = l & 15, g = l >> 4;

    f32x4 acc[12];
    #pragma unroll
    for (int f = 0; f < 12; ++f) acc[f] = (f32x4){0.f, 0.f, 0.f, 0.f};

    const float* xp = x + (row0 + l15) * E + kh * 512 + g * 8;
    const short* wp = Wb + (size_t)(kh * 16) * 12 * 512 + (size_t)l * 8;

    for (int kc = 0; kc < 16; ++kc) {
        float4 a0 = *(const float4*)(xp);
        float4 a1 = *(const float4*)(xp + 4);
        xp += 32;
        bf16x8 af;
        af[0] = f2bf(a0.x); af[1] = f2bf(a0.y); af[2] = f2bf(a0.z); af[3] = f2bf(a0.w);
        af[4] = f2bf(a1.x); af[5] = f2bf(a1.y); af[6] = f2bf(a1.z); af[7] = f2bf(a1.w);
        #pragma unroll
        for (int f = 0; f < 12; ++f) {
            bf16x8 bf = *(const bf16x8*)(wp + (size_t)f * 512);
            acc[f] = __builtin_amdgcn_mfma_f32_16x16x32_bf16(af, bf, acc[f], 0, 0, 0);
        }
        wp += 12 * 512;
    }

    if (kh == 1) {
        #pragma unroll
        for (int f = 0; f < 12; ++f)
            *(f32x4*)&part[wm][f][l][0] = acc[f];
    }
    __syncthreads();
    if (kh == 0) {
        #pragma unroll
        for (int f = 0; f < 12; ++f)
            acc[f] += *(const f32x4*)&part[wm][f][l][0];
        #pragma unroll
        for (int f = 0; f < 12; ++f) {
            const int m = f >> 2;
            const int h = ((f & 3) << 4) + l15;
            if (m == 2) {
                // Vt[b][h][t], pack 4 consecutive t into one 8B store
                const long row = row0 + g * 4;
                const long bb = row >> 11;
                const int  t0 = (int)(row & 2047);
                short4v pkt;
                #pragma unroll
                for (int r = 0; r < 4; ++r) pkt[r] = f2bf(acc[f][r]);
                *(short4v*)&vt[(bb * 64 + h) * TT + t0] = pkt;
            } else {
                short* base = (m == 0) ? q : k;
                const float sc = (m == 0) ? 0.125f : 1.0f;   // fold 1/sqrt(H) into q
                #pragma unroll
                for (int r = 0; r < 4; ++r) {
                    const long row = row0 + g * 4 + r;
                    base[row * 64 + h] = f2bf(acc[f][r] * sc);
                }
            }
        }
    }
}

// ---------------- Barrier-free MFMA flash attention ----------------
// Block = one 16-row q-tile, 4 independent waves; wave w takes kv-chunks
// {w*64 + i*256}. Own flash state per wave; single merge barrier at end.
// K fragments from global k (row-major), V fragments from global Vt.
__global__ __launch_bounds__(256)
void attn_v3(const short* __restrict__ qg,
             const short* __restrict__ kg,
             const short* __restrict__ vtg,
             float* __restrict__ out)
{
    __shared__ short Ps[4][16 * 64];     // per-wave P round-trip, swizzled
    __shared__ float Op[4][16][68];      // per-wave O partials
    __shared__ float Ml[4][16][2];       // per-wave (m, l)

    const int t   = threadIdx.x;
    const int L   = t & 63;
    const int w   = t >> 6;              // wave id = kv interleave slot
    const int b   = blockIdx.y;
    const int st  = 127 - (int)blockIdx.x;   // LPT: heavy tiles first
    const int q0  = st * 16;
    const int qhi = q0 + 15;
    const int l15 = L & 15, g = L >> 4;

    // Q fragments (A-layout: row=l15, k=g*8+j (+32 per kc))
    bf16x8 qf[2];
    {
        const short* qp = qg + ((long)b * TT + q0 + l15) * 64 + g * 8;
        qf[0] = *(const bf16x8*)(qp);
        qf[1] = *(const bf16x8*)(qp + 32);
    }

    const f32x4 zero4 = {0.f, 0.f, 0.f, 0.f};
    f32x4 o[4] = {zero4, zero4, zero4, zero4};
    float mrun[4], lrun[4];
    #pragma unroll
    for (int r = 0; r < 4; ++r) { mrun[r] = -1e30f; lrun[r] = 0.f; }

    const short* kbase  = kg  + (long)b * TT * 64;
    const short* vtbase = vtg + (long)b * 64 * TT;

    for (int kv0 = w * 64; kv0 <= qhi; kv0 += 256) {
        // ---- QK^T: K B-frags straight from global (L2-resident) ----
        f32x4 s[4];
        #pragma unroll
        for (int c = 0; c < 4; ++c) s[c] = zero4;
        #pragma unroll
        for (int c = 0; c < 4; ++c) {
            const short* kp = kbase + (long)(kv0 + c * 16 + l15) * 64 + g * 8;
            #pragma unroll
            for (int kc = 0; kc < 2; ++kc) {
                bf16x8 kf = *(const bf16x8*)(kp + kc * 32);
                s[c] = __builtin_amdgcn_mfma_f32_16x16x32_bf16(qf[kc], kf, s[c], 0, 0, 0);
            }
        }
        if (kv0 + 63 > q0) {   // chunk overlaps diagonal -> per-element mask
            #pragma unroll
            for (int c = 0; c < 4; ++c) {
                const int kvg = kv0 + c * 16 + l15;
                #pragma unroll
                for (int r = 0; r < 4; ++r)
                    if (kvg > q0 + g * 4 + r) s[c][r] = -1e30f;
            }
        }
        // ---- in-wave online softmax ----
        float alpha[4];
        #pragma unroll
        for (int r = 0; r < 4; ++r) {
            float m = fmaxf(fmaxf(s[0][r], s[1][r]), fmaxf(s[2][r], s[3][r]));
            m = fmaxf(m, __shfl_xor(m, 1));
            m = fmaxf(m, __shfl_xor(m, 2));
            m = fmaxf(m, __shfl_xor(m, 4));
            m = fmaxf(m, __shfl_xor(m, 8));
            const float mnew = fmaxf(mrun[r], m);
            alpha[r] = __expf(mrun[r] - mnew);
            mrun[r] = mnew;
            #pragma unroll
            for (int nf = 0; nf < 4; ++nf) o[nf][r] *= alpha[r];
        }
        float lsum[4] = {0.f, 0.f, 0.f, 0.f};
        #pragma unroll
        for (int c = 0; c < 4; ++c)
            #pragma unroll
            for (int r = 0; r < 4; ++r) {
                float p = __expf(s[c][r] - mrun[r]);
                s[c][r] = p;
                lsum[r] += p;
            }
        #pragma unroll
        for (int r = 0; r < 4; ++r) {
            lsum[r] += __shfl_xor(lsum[r], 1);
            lsum[r] += __shfl_xor(lsum[r], 2);
            lsum[r] += __shfl_xor(lsum[r], 4);
            lsum[r] += __shfl_xor(lsum[r], 8);
            lrun[r] = lrun[r] * alpha[r] + lsum[r];
        }
        // ---- P -> wave-local LDS (transpose to A-frag layout) ----
        #pragma unroll
        for (int c = 0; c < 4; ++c)
            #pragma unroll
            for (int r = 0; r < 4; ++r) {
                const int ql = g * 4 + r, kvl = c * 16 + l15;
                Ps[w][(ql * 64 + kvl) ^ ((ql & 7) << 3)] = f2bf(s[c][r]);
            }
        // ---- PV: V B-frags straight from global Vt ----
        #pragma unroll
        for (int kc = 0; kc < 2; ++kc) {
            bf16x8 pa = *(const bf16x8*)&Ps[w][(l15 * 64 + kc * 32 + g * 8) ^ ((l15 & 7) << 3)];
            #pragma unroll
            for (int nf = 0; nf < 4; ++nf) {
                bf16x8 vb = *(const bf16x8*)(vtbase + (long)(nf * 16 + l15) * TT + kv0 + kc * 32 + g * 8);
                o[nf] = __builtin_amdgcn_mfma_f32_16x16x32_bf16(pa, vb, o[nf], 0, 0, 0);
            }
        }
    }

    // ---- publish partials, single barrier, 4-way merge ----
    #pragma unroll
    for (int nf = 0; nf < 4; ++nf)
        #pragma unroll
        for (int r = 0; r < 4; ++r)
            Op[w][g * 4 + r][nf * 16 + l15] = o[nf][r];
    if (l15 == 0) {
        #pragma unroll
        for (int r = 0; r < 4; ++r) {
            Ml[w][g * 4 + r][0] = mrun[r];
            Ml[w][g * 4 + r][1] = lrun[r];
        }
    }
    __syncthreads();

    // wave w merges rows w*4..w*4+3; lane L handles output column L
    #pragma unroll
    for (int rr = 0; rr < 4; ++rr) {
        const int row = w * 4 + rr;
        float m0 = Ml[0][row][0], m1 = Ml[1][row][0];
        float m2 = Ml[2][row][0], m3 = Ml[3][row][0];
        float M = fmaxf(fmaxf(m0, m1), fmaxf(m2, m3));
        float a0 = __expf(m0 - M), a1 = __expf(m1 - M);
        float a2 = __expf(m2 - M), a3 = __expf(m3 - M);
        float Ls = a0 * Ml[0][row][1] + a1 * Ml[1][row][1] +
                   a2 * Ml[2][row][1] + a3 * Ml[3][row][1];
        float val = a0 * Op[0][row][L] + a1 * Op[1][row][L] +
                    a2 * Op[2][row][L] + a3 * Op[3][row][L];
        out[((long)b * TT + q0 + row) * 64 + L] = val / Ls;
    }
}

extern "C" void kernel_launch(void* const* d_in, const int* in_sizes, int n_in,
                              void* d_out, int out_size, void* d_ws, size_t ws_size,
                              hipStream_t stream)
{
    const float* x  = (const float*)d_in[0];
    const float* Wq = (const float*)d_in[1];
    const float* Wk = (const float*)d_in[2];
    const float* Wv = (const float*)d_in[3];
    float* out = (float*)d_out;

    const size_t n = (size_t)BB * TT * H;   // 1,048,576 per tensor
    short* q  = (short*)d_ws;
    short* k  = q + n;
    short* vt = k + n;                      // V transposed: [B][H][T]
    short* Wb = vt + n;                     // 196,608 shorts

    pack_w   <<<dim3(96),      256, 0, stream>>>(Wq, Wk, Wv, Wb);
    proj_mfma<<<dim3(512),     256, 0, stream>>>(x, Wb, q, k, vt);
    attn_v3  <<<dim3(128, BB), 256, 0, stream>>>(q, k, vt, out);
}

// Round 5
// 87.183 us; speedup vs baseline: 3.7060x; 1.0145x over previous
//
#include <hip/hip_runtime.h>

#define E  1024
#define H  64
#define BB 8
#define TT 2048

typedef __attribute__((ext_vector_type(8))) short bf16x8;
typedef __attribute__((ext_vector_type(4))) float f32x4;
typedef __attribute__((ext_vector_type(8))) short short8;
typedef __attribute__((ext_vector_type(4))) short short4v;

__device__ __forceinline__ short f2bf(float f) {
    union { float f; unsigned u; } v; v.f = f;
    unsigned r = v.u + 0x7FFFu + ((v.u >> 16) & 1u);   // RNE
    return (short)(r >> 16);
}

// ---- pack W into B-fragment layout for mfma_f32_16x16x32_bf16 ----
__global__ __launch_bounds__(256)
void pack_w(const float* __restrict__ Wq, const float* __restrict__ Wk,
            const float* __restrict__ Wv, short* __restrict__ Wb)
{
    const int t  = blockIdx.x * 256 + threadIdx.x;   // 24576 total
    const int l  = t & 63;
    const int f  = (t >> 6) % 12;
    const int kc = t / 768;                          // kchunk 0..31
    const float* W = (f < 4) ? Wq : ((f < 8) ? Wk : Wv);
    const int e0 = kc * 32 + ((l >> 4) << 3);
    const int n  = ((f & 3) << 4) + (l & 15);
    short8 o;
    #pragma unroll
    for (int j = 0; j < 8; ++j) o[j] = f2bf(W[(e0 + j) * 64 + n]);
    *(short8*)&Wb[(size_t)t * 8] = o;
}

// ---- split-K MFMA projection; writes q,k row-major and V TRANSPOSED ----
__global__ __launch_bounds__(256)
void proj_mfma(const float* __restrict__ x, const short* __restrict__ Wb,
               short* __restrict__ q, short* __restrict__ k, short* __restrict__ vt)
{
    __shared__ float part[2][12][64][4];   // 24 KB: kh=1 partials
    const int t   = threadIdx.x;
    const int l   = t & 63;
    const int wid = t >> 6;
    const int wm  = wid & 1, kh = wid >> 1;
    const long row0 = (long)blockIdx.x * 32 + wm * 16;
    const int l15 = l & 15, g = l >> 4;

    f32x4 acc[12];
    #pragma unroll
    for (int f = 0; f < 12; ++f) acc[f] = (f32x4){0.f, 0.f, 0.f, 0.f};

    const float* xp = x + (row0 + l15) * E + kh * 512 + g * 8;
    const short* wp = Wb + (size_t)(kh * 16) * 12 * 512 + (size_t)l * 8;

    for (int kc = 0; kc < 16; ++kc) {
        float4 a0 = *(const float4*)(xp);
        float4 a1 = *(const float4*)(xp + 4);
        xp += 32;
        bf16x8 af;
        af[0] = f2bf(a0.x); af[1] = f2bf(a0.y); af[2] = f2bf(a0.z); af[3] = f2bf(a0.w);
        af[4] = f2bf(a1.x); af[5] = f2bf(a1.y); af[6] = f2bf(a1.z); af[7] = f2bf(a1.w);
        #pragma unroll
        for (int f = 0; f < 12; ++f) {
            bf16x8 bf = *(const bf16x8*)(wp + (size_t)f * 512);
            acc[f] = __builtin_amdgcn_mfma_f32_16x16x32_bf16(af, bf, acc[f], 0, 0, 0);
        }
        wp += 12 * 512;
    }

    if (kh == 1) {
        #pragma unroll
        for (int f = 0; f < 12; ++f)
            *(f32x4*)&part[wm][f][l][0] = acc[f];
    }
    __syncthreads();
    if (kh == 0) {
        #pragma unroll
        for (int f = 0; f < 12; ++f)
            acc[f] += *(const f32x4*)&part[wm][f][l][0];
        #pragma unroll
        for (int f = 0; f < 12; ++f) {
            const int m = f >> 2;
            const int h = ((f & 3) << 4) + l15;
            if (m == 2) {
                // Vt[b][h][t], pack 4 consecutive t into one 8B store
                const long row = row0 + g * 4;
                const long bb = row >> 11;
                const int  t0 = (int)(row & 2047);
                short4v pkt;
                #pragma unroll
                for (int r = 0; r < 4; ++r) pkt[r] = f2bf(acc[f][r]);
                *(short4v*)&vt[(bb * 64 + h) * TT + t0] = pkt;
            } else {
                short* base = (m == 0) ? q : k;
                // fold 1/sqrt(H) AND log2(e) into q -> softmax uses exp2
                const float sc = (m == 0) ? (0.125f * 1.44269504f) : 1.0f;
                #pragma unroll
                for (int r = 0; r < 4; ++r) {
                    const long row = row0 + g * 4 + r;
                    base[row * 64 + h] = f2bf(acc[f][r] * sc);
                }
            }
        }
    }
}

// -------- Barrier-free, software-pipelined MFMA flash attention --------
// Block = one 16-row q-tile, 4 independent waves; wave w takes kv-chunks
// {w*64 + i*256}. 2-deep pipeline: while softmax/PV of chunk i runs,
// K(i+1) is loaded and QK(i+1) is computed; V(i) prefetched to regs.
__global__ __launch_bounds__(256)
void attn_v4(const short* __restrict__ qg,
             const short* __restrict__ kg,
             const short* __restrict__ vtg,
             float* __restrict__ out)
{
    __shared__ short Ps[4][16 * 64];     // per-wave P round-trip, swizzled
    __shared__ float Op[4][16][68];      // per-wave O partials
    __shared__ float Ml[4][16][2];       // per-wave (m, l)

    const int t   = threadIdx.x;
    const int L   = t & 63;
    const int w   = t >> 6;
    const int b   = blockIdx.y;
    const int st  = 127 - (int)blockIdx.x;   // LPT: heavy tiles first
    const int q0  = st * 16;
    const int qhi = q0 + 15;
    const int l15 = L & 15, g = L >> 4;

    bf16x8 qf[2];
    {
        const short* qp = qg + ((long)b * TT + q0 + l15) * 64 + g * 8;
        qf[0] = *(const bf16x8*)(qp);
        qf[1] = *(const bf16x8*)(qp + 32);
    }

    const f32x4 zero4 = {0.f, 0.f, 0.f, 0.f};
    f32x4 o[4] = {zero4, zero4, zero4, zero4};
    float mrun[4], lrun[4];
    #pragma unroll
    for (int r = 0; r < 4; ++r) { mrun[r] = -1e30f; lrun[r] = 0.f; }

    const short* kbase  = kg  + (long)b * TT * 64;
    const short* vtbase = vtg + (long)b * 64 * TT;

    int kv = w * 64;
    if (kv <= qhi) {
        bf16x8 kf[8], vf[8];

        // prologue: K(first) + QK(first)
        #pragma unroll
        for (int c = 0; c < 4; ++c)
            #pragma unroll
            for (int kc = 0; kc < 2; ++kc)
                kf[c * 2 + kc] = *(const bf16x8*)(kbase + (long)(kv + c * 16 + l15) * 64 + kc * 32 + g * 8);
        f32x4 s[4];
        #pragma unroll
        for (int c = 0; c < 4; ++c) s[c] = zero4;
        __builtin_amdgcn_s_setprio(1);
        #pragma unroll
        for (int c = 0; c < 4; ++c)
            #pragma unroll
            for (int kc = 0; kc < 2; ++kc)
                s[c] = __builtin_amdgcn_mfma_f32_16x16x32_bf16(qf[kc], kf[c * 2 + kc], s[c], 0, 0, 0);
        __builtin_amdgcn_s_setprio(0);

        int kvs = kv;            // chunk id currently held in s
        kv += 256;
        bool hasnext = (kv <= qhi);
        if (hasnext) {
            #pragma unroll
            for (int c = 0; c < 4; ++c)
                #pragma unroll
                for (int kc = 0; kc < 2; ++kc)
                    kf[c * 2 + kc] = *(const bf16x8*)(kbase + (long)(kv + c * 16 + l15) * 64 + kc * 32 + g * 8);
        }

        while (true) {
            // ---- issue V(cur) loads early (used at the end of this iter) ----
            #pragma unroll
            for (int nf = 0; nf < 4; ++nf)
                #pragma unroll
                for (int kc = 0; kc < 2; ++kc)
                    vf[nf * 2 + kc] = *(const bf16x8*)(vtbase + (long)(nf * 16 + l15) * TT + kvs + kc * 32 + g * 8);

            // ---- causal mask (diagonal chunks only) ----
            if (kvs + 63 > q0) {
                #pragma unroll
                for (int c = 0; c < 4; ++c) {
                    const int kvg = kvs + c * 16 + l15;
                    #pragma unroll
                    for (int r = 0; r < 4; ++r)
                        if (kvg > q0 + g * 4 + r) s[c][r] = -1e30f;
                }
            }
            // ---- row max ----
            float mloc[4];
            #pragma unroll
            for (int r = 0; r < 4; ++r) {
                float m = fmaxf(fmaxf(s[0][r], s[1][r]), fmaxf(s[2][r], s[3][r]));
                m = fmaxf(m, __shfl_xor(m, 1));
                m = fmaxf(m, __shfl_xor(m, 2));
                m = fmaxf(m, __shfl_xor(m, 4));
                m = fmaxf(m, __shfl_xor(m, 8));
                mloc[r] = m;
            }
            // ---- defer-max: rescale only when the max really grows ----
            bool ok = (mloc[0] <= mrun[0] + 8.f) && (mloc[1] <= mrun[1] + 8.f) &&
                      (mloc[2] <= mrun[2] + 8.f) && (mloc[3] <= mrun[3] + 8.f);
            if (!__all(ok)) {
                #pragma unroll
                for (int r = 0; r < 4; ++r) {
                    const float mnew = fmaxf(mrun[r], mloc[r]);
                    const float a = exp2f(mrun[r] - mnew);
                    mrun[r] = mnew;
                    lrun[r] *= a;
                    #pragma unroll
                    for (int nf = 0; nf < 4; ++nf) o[nf][r] *= a;
                }
            }
            // ---- p = exp2(s-m), Ps write, lsum ----
            float lsum[4] = {0.f, 0.f, 0.f, 0.f};
            #pragma unroll
            for (int c = 0; c < 4; ++c)
                #pragma unroll
                for (int r = 0; r < 4; ++r) {
                    float p = exp2f(s[c][r] - mrun[r]);
                    lsum[r] += p;
                    const int ql = g * 4 + r, kvl = c * 16 + l15;
                    Ps[w][(ql * 64 + kvl) ^ ((ql & 7) << 3)] = f2bf(p);
                }
            #pragma unroll
            for (int r = 0; r < 4; ++r) {
                lsum[r] += __shfl_xor(lsum[r], 1);
                lsum[r] += __shfl_xor(lsum[r], 2);
                lsum[r] += __shfl_xor(lsum[r], 4);
                lsum[r] += __shfl_xor(lsum[r], 8);
                lrun[r] += lsum[r];
            }
            // ---- QK for NEXT chunk (covers Ps write->read + V latency) ----
            if (hasnext) {
                #pragma unroll
                for (int c = 0; c < 4; ++c) s[c] = zero4;
                __builtin_amdgcn_s_setprio(1);
                #pragma unroll
                for (int c = 0; c < 4; ++c)
                    #pragma unroll
                    for (int kc = 0; kc < 2; ++kc)
                        s[c] = __builtin_amdgcn_mfma_f32_16x16x32_bf16(qf[kc], kf[c * 2 + kc], s[c], 0, 0, 0);
                __builtin_amdgcn_s_setprio(0);
            }
            // ---- PV for CURRENT chunk ----
            __builtin_amdgcn_s_setprio(1);
            #pragma unroll
            for (int kc = 0; kc < 2; ++kc) {
                bf16x8 pa = *(const bf16x8*)&Ps[w][(l15 * 64 + kc * 32 + g * 8) ^ ((l15 & 7) << 3)];
                #pragma unroll
                for (int nf = 0; nf < 4; ++nf)
                    o[nf] = __builtin_amdgcn_mfma_f32_16x16x32_bf16(pa, vf[nf * 2 + kc], o[nf], 0, 0, 0);
            }
            __builtin_amdgcn_s_setprio(0);

            if (!hasnext) break;
            kvs = kv;
            kv += 256;
            hasnext = (kv <= qhi);
            if (hasnext) {
                #pragma unroll
                for (int c = 0; c < 4; ++c)
                    #pragma unroll
                    for (int kc = 0; kc < 2; ++kc)
                        kf[c * 2 + kc] = *(const bf16x8*)(kbase + (long)(kv + c * 16 + l15) * 64 + kc * 32 + g * 8);
            }
        }
    }

    // ---- publish partials, single barrier, 4-way merge ----
    #pragma unroll
    for (int nf = 0; nf < 4; ++nf)
        #pragma unroll
        for (int r = 0; r < 4; ++r)
            Op[w][g * 4 + r][nf * 16 + l15] = o[nf][r];
    if (l15 == 0) {
        #pragma unroll
        for (int r = 0; r < 4; ++r) {
            Ml[w][g * 4 + r][0] = mrun[r];
            Ml[w][g * 4 + r][1] = lrun[r];
        }
    }
    __syncthreads();

    #pragma unroll
    for (int rr = 0; rr < 4; ++rr) {
        const int row = w * 4 + rr;
        float m0 = Ml[0][row][0], m1 = Ml[1][row][0];
        float m2 = Ml[2][row][0], m3 = Ml[3][row][0];
        float M = fmaxf(fmaxf(m0, m1), fmaxf(m2, m3));
        float a0 = exp2f(m0 - M), a1 = exp2f(m1 - M);
        float a2 = exp2f(m2 - M), a3 = exp2f(m3 - M);
        float Ls = a0 * Ml[0][row][1] + a1 * Ml[1][row][1] +
                   a2 * Ml[2][row][1] + a3 * Ml[3][row][1];
        float val = a0 * Op[0][row][L] + a1 * Op[1][row][L] +
                    a2 * Op[2][row][L] + a3 * Op[3][row][L];
        out[((long)b * TT + q0 + row) * 64 + L] = val / Ls;
    }
}

extern "C" void kernel_launch(void* const* d_in, const int* in_sizes, int n_in,
                              void* d_out, int out_size, void* d_ws, size_t ws_size,
                              hipStream_t stream)
{
    const float* x  = (const float*)d_in[0];
    const float* Wq = (const float*)d_in[1];
    const float* Wk = (const float*)d_in[2];
    const float* Wv = (const float*)d_in[3];
    float* out = (float*)d_out;

    const size_t n = (size_t)BB * TT * H;   // 1,048,576 per tensor
    short* q  = (short*)d_ws;
    short* k  = q + n;
    short* vt = k + n;                      // V transposed: [B][H][T]
    short* Wb = vt + n;                     // 196,608 shorts

    pack_w   <<<dim3(96),      256, 0, stream>>>(Wq, Wk, Wv, Wb);
    proj_mfma<<<dim3(512),     256, 0, stream>>>(x, Wb, q, k, vt);
    attn_v4  <<<dim3(128, BB), 256, 0, stream>>>(q, k, vt, out);
}